// Round 1
// baseline (703.706 us; speedup 1.0000x reference)
//
#include <hip/hip_runtime.h>
#include <hip/hip_bf16.h>
#include <stdint.h>

// ConvIntrinsic: fused  out[k,o,t] = relu( Σ_f sw[t,f]·ms[k,f]
//                + Σ_{x,y,f} W3[o,t,x,y,f]·interp0[k,x,y,f] + bias[t] )
// W3[o,t,x,y,f] = Σ_{r,a} tw[t,r,(a+o)&7,f]·kernel[r,a,x,y]   (prep kernel)
// interp0[k,x,y,f] = Σ_j bw[k,x,y,j]·ms[idx[k,x,y,j], f]       (built on the fly)
// => GEMM (K=100000 × 1312) @ (1312 × 768), o=8 column duplicates o=0.

typedef __attribute__((ext_vector_type(8))) short short8;
typedef __attribute__((ext_vector_type(4))) float floatx4;

#define KPTS 100000
#define OUT_STRIDE 864   // 9*96
#define NCH 41           // 40 neighbor chunks (x,y) + 1 center chunk
#define BM 128
#define THREADS 512

__device__ __forceinline__ short f2bf(float x) {
  union { float f; uint32_t u; } c; c.f = x;
  uint32_t u = c.u;
  u += 0x7FFFu + ((u >> 16) & 1u);   // round-to-nearest-even
  return (short)(u >> 16);
}

// ---------------- prep: pack B in MFMA fragment layout --------------------
// Bp[ch][ntile][lane][j] = B[c = ch*32 + (lane>>4)*8 + j][n = ntile*16 + (lane&15)]
__global__ void prep_B(const float* __restrict__ kern,
                       const float* __restrict__ tw,
                       const float* __restrict__ sw,
                       short* __restrict__ Bp) {
  const int ntile = blockIdx.x;   // 0..47
  const int ch    = blockIdx.y;   // 0..40
  const int lane  = threadIdx.x;  // 0..63
  const int n = ntile * 16 + (lane & 15);
  const int o = n / 96;
  const int t = n - o * 96;
  const int fb = (lane >> 4) * 8;

  short8 v;
  if (ch < 40) {
    float kcol[40];
#pragma unroll
    for (int ra = 0; ra < 40; ++ra) kcol[ra] = kern[ra * 40 + ch];
#pragma unroll
    for (int j = 0; j < 8; ++j) {
      const int f = fb + j;
      float acc = 0.f;
      for (int r = 0; r < 5; ++r) {
#pragma unroll
        for (int a = 0; a < 8; ++a) {
          acc += kcol[r * 8 + a] * tw[((t * 5 + r) * 8 + ((a + o) & 7)) * 32 + f];
        }
      }
      v[j] = f2bf(acc);
    }
  } else {
#pragma unroll
    for (int j = 0; j < 8; ++j) v[j] = f2bf(sw[t * 32 + fb + j]);
  }
  *reinterpret_cast<short8*>(Bp + ((size_t)(ch * 48 + ntile) * 64 + lane) * 8) = v;
}

// ---------------- main fused GEMM ----------------------------------------
__global__ __launch_bounds__(THREADS, 1) void conv_main(
    const float* __restrict__ ms,
    const float* __restrict__ bary,
    const float* __restrict__ bias,
    const short* __restrict__ Bp,
    float* __restrict__ out) {
  __shared__ short Atile[2][BM][40];   // stride 40: 16B aligned rows, 2-way bank alias (free)

  const int kbase = blockIdx.x * BM;
  const int bn = blockIdx.y;            // 0..1  (N halves of 384)
  const int tid = threadIdx.x;
  const int lane = tid & 63;
  const int wid = tid >> 6;             // 0..7
  const int wm = wid >> 2;              // 0..1
  const int wn = wid & 3;               // 0..3
  const int l15 = lane & 15;
  const int kh = lane >> 4;             // 0..3

  // A-build role: 4 threads per row, 8 f-columns each
  const int arow = tid >> 2;            // 0..127
  const int af0 = (tid & 3) * 8;
  const int krow = kbase + arow;

  auto build = [&](int ch, int buf) {
    float v[8];
    if (krow < KPTS) {
      if (ch < 40) {
        const float* bp = bary + (size_t)krow * 240 + ch * 6;
        float2 p0 = *(const float2*)(bp);
        float2 p1 = *(const float2*)(bp + 2);
        float2 p2 = *(const float2*)(bp + 4);
        const float* m0 = ms + ((size_t)(int)p0.x) * 32 + af0;
        const float* m1 = ms + ((size_t)(int)p1.x) * 32 + af0;
        const float* m2 = ms + ((size_t)(int)p2.x) * 32 + af0;
        float4 a0 = *(const float4*)(m0), b0 = *(const float4*)(m0 + 4);
        float4 a1 = *(const float4*)(m1), b1 = *(const float4*)(m1 + 4);
        float4 a2 = *(const float4*)(m2), b2 = *(const float4*)(m2 + 4);
        v[0] = p0.y * a0.x + p1.y * a1.x + p2.y * a2.x;
        v[1] = p0.y * a0.y + p1.y * a1.y + p2.y * a2.y;
        v[2] = p0.y * a0.z + p1.y * a1.z + p2.y * a2.z;
        v[3] = p0.y * a0.w + p1.y * a1.w + p2.y * a2.w;
        v[4] = p0.y * b0.x + p1.y * b1.x + p2.y * b2.x;
        v[5] = p0.y * b0.y + p1.y * b1.y + p2.y * b2.y;
        v[6] = p0.y * b0.z + p1.y * b1.z + p2.y * b2.z;
        v[7] = p0.y * b0.w + p1.y * b1.w + p2.y * b2.w;
      } else {  // center chunk: A[k][1280+f] = ms[k][f]
        const float* m = ms + (size_t)krow * 32 + af0;
        float4 a = *(const float4*)m, b = *(const float4*)(m + 4);
        v[0] = a.x; v[1] = a.y; v[2] = a.z; v[3] = a.w;
        v[4] = b.x; v[5] = b.y; v[6] = b.z; v[7] = b.w;
      }
    } else {
#pragma unroll
      for (int j = 0; j < 8; ++j) v[j] = 0.f;
    }
    short8 s;
#pragma unroll
    for (int j = 0; j < 8; ++j) s[j] = f2bf(v[j]);
    *reinterpret_cast<short8*>(&Atile[buf][arow][af0]) = s;
  };

  floatx4 acc[4][6];
#pragma unroll
  for (int mi = 0; mi < 4; ++mi)
#pragma unroll
    for (int nj = 0; nj < 6; ++nj) acc[mi][nj] = (floatx4)0.f;

  const int ntbase = bn * 24 + wn * 6;  // global n-tile base for this wave

  build(0, 0);
  __syncthreads();

  for (int ch = 0; ch < NCH; ++ch) {
    const int cur = ch & 1;
    if (ch < 40) build(ch + 1, cur ^ 1);   // overlap next-chunk build with MFMA

    short8 afrag[4];
    const short* ap = &Atile[cur][wm * 64 + l15][kh * 8];
#pragma unroll
    for (int mi = 0; mi < 4; ++mi)
      afrag[mi] = *reinterpret_cast<const short8*>(ap + mi * 16 * 40);

    const short* bbase = Bp + ((size_t)(ch * 48 + ntbase) * 64 + lane) * 8;
#pragma unroll
    for (int nj = 0; nj < 6; ++nj) {
      short8 bfrag = *reinterpret_cast<const short8*>(bbase + (size_t)nj * 64 * 8);
#pragma unroll
      for (int mi = 0; mi < 4; ++mi)
        acc[mi][nj] = __builtin_amdgcn_mfma_f32_16x16x32_bf16(afrag[mi], bfrag, acc[mi][nj], 0, 0, 0);
    }
    __syncthreads();
  }

  // epilogue: bias + relu, write out[k, o, t] = out[k*864 + n]; duplicate o=8 from o=0
  const int row0 = kbase + wm * 64 + kh * 4;
  const int col0 = bn * 384 + wn * 96;
#pragma unroll
  for (int mi = 0; mi < 4; ++mi) {
    const int rb = row0 + mi * 16;
#pragma unroll
    for (int nj = 0; nj < 6; ++nj) {
      const int n = col0 + nj * 16 + l15;
      const float bsv = bias[n % 96];
      const bool dup = (n < 96);
#pragma unroll
      for (int i = 0; i < 4; ++i) {
        const int r = rb + i;
        if (r < KPTS) {
          float vv = fmaxf(acc[mi][nj][i] + bsv, 0.f);
          out[(size_t)r * OUT_STRIDE + n] = vv;
          if (dup) out[(size_t)r * OUT_STRIDE + 768 + n] = vv;
        }
      }
    }
  }
}

extern "C" void kernel_launch(void* const* d_in, const int* in_sizes, int n_in,
                              void* d_out, int out_size, void* d_ws, size_t ws_size,
                              hipStream_t stream) {
  const float* ms   = (const float*)d_in[0];  // (K,32)
  const float* bary = (const float*)d_in[1];  // (K,5,8,3,2)
  const float* kern = (const float*)d_in[2];  // (5,8,5,8)
  const float* tw   = (const float*)d_in[3];  // (96,5,8,32)
  const float* sw   = (const float*)d_in[4];  // (96,1,32)
  const float* bias = (const float*)d_in[5];  // (96,)
  float* out = (float*)d_out;
  short* Bp = (short*)d_ws;                   // 41*48*64*8 bf16 ≈ 2.02 MB

  hipLaunchKernelGGL(prep_B, dim3(48, 41), dim3(64), 0, stream, kern, tw, sw, Bp);
  hipLaunchKernelGGL(conv_main, dim3(782, 2), dim3(THREADS), 0, stream,
                     ms, bary, bias, Bp, out);
}

// Round 2
// 535.016 us; speedup vs baseline: 1.3153x; 1.3153x over previous
//
#include <hip/hip_runtime.h>
#include <hip/hip_bf16.h>
#include <stdint.h>

// ConvIntrinsic: fused  out[k,o,t] = relu( Σ_f sw[t,f]·ms[k,f]
//                + Σ_{x,y,f} W3[o,t,x,y,f]·interp0[k,x,y,f] + bias[t] )
// W3[o,t,x,y,f] = Σ_{r,a} tw[t,r,(a+o)&7,f]·kernel[r,a,x,y]   (prep kernel)
// interp0[k,x,y,f] = Σ_j bw[k,x,y,j]·ms[idx[k,x,y,j], f]       (built on the fly)
// => GEMM (K=100000 × 1312) @ (1312 × 768), o=8 column duplicates o=0.
//
// R1: latency restructure (T14). Old build() waited gather vmcnt + ds_write
// BEFORE the MFMA section -> fully exposed ~1.5k+ cy/chunk. Now: issue
// gathers early (bary pre-loaded 3 chunks ahead), MFMA on current buffer,
// THEN wait+convert+ds_write next buffer. B-fragments prefetched 1 chunk
// ahead into regs.

typedef __attribute__((ext_vector_type(8))) short short8;
typedef __attribute__((ext_vector_type(4))) float floatx4;

#define KPTS 100000
#define OUT_STRIDE 864   // 9*96
#define NCH 41           // 40 neighbor chunks (x,y) + 1 center chunk
#define BM 128
#define THREADS 512

__device__ __forceinline__ short f2bf(float x) {
  union { float f; uint32_t u; } c; c.f = x;
  uint32_t u = c.u;
  u += 0x7FFFu + ((u >> 16) & 1u);   // round-to-nearest-even
  return (short)(u >> 16);
}

// ---------------- prep: pack B in MFMA fragment layout --------------------
// Bp[ch][ntile][lane][j] = B[c = ch*32 + (lane>>4)*8 + j][n = ntile*16 + (lane&15)]
__global__ void prep_B(const float* __restrict__ kern,
                       const float* __restrict__ tw,
                       const float* __restrict__ sw,
                       short* __restrict__ Bp) {
  const int ntile = blockIdx.x;   // 0..47
  const int ch    = blockIdx.y;   // 0..40
  const int lane  = threadIdx.x;  // 0..63
  const int n = ntile * 16 + (lane & 15);
  const int o = n / 96;
  const int t = n - o * 96;
  const int fb = (lane >> 4) * 8;

  short8 v;
  if (ch < 40) {
    float kcol[40];
#pragma unroll
    for (int ra = 0; ra < 40; ++ra) kcol[ra] = kern[ra * 40 + ch];
#pragma unroll
    for (int j = 0; j < 8; ++j) {
      const int f = fb + j;
      float acc = 0.f;
      for (int r = 0; r < 5; ++r) {
#pragma unroll
        for (int a = 0; a < 8; ++a) {
          acc += kcol[r * 8 + a] * tw[((t * 5 + r) * 8 + ((a + o) & 7)) * 32 + f];
        }
      }
      v[j] = f2bf(acc);
    }
  } else {
#pragma unroll
    for (int j = 0; j < 8; ++j) v[j] = f2bf(sw[t * 32 + fb + j]);
  }
  *reinterpret_cast<short8*>(Bp + ((size_t)(ch * 48 + ntile) * 64 + lane) * 8) = v;
}

// ---------------- main fused GEMM ----------------------------------------
__global__ __launch_bounds__(THREADS, 1) void conv_main(
    const float* __restrict__ ms,
    const float* __restrict__ bary,
    const float* __restrict__ bias,
    const short* __restrict__ Bp,
    float* __restrict__ out) {
  __shared__ short Atile[2][BM][40];   // stride 40 shorts: 2-way bank alias (free)

  const int kbase = blockIdx.x * BM;
  const int bn = blockIdx.y;            // 0..1  (N halves of 384)
  const int tid = threadIdx.x;
  const int lane = tid & 63;
  const int wid = tid >> 6;             // 0..7
  const int wm = wid >> 2;              // 0..1
  const int wn = wid & 3;               // 0..3
  const int l15 = lane & 15;
  const int kh = lane >> 4;             // 0..3

  // A-build role: 4 threads per row, 8 f-columns each
  const int arow = tid >> 2;            // 0..127
  const int af0 = (tid & 3) * 8;
  const int krow = kbase + arow;
  const bool rowok = krow < KPTS;
  const float* __restrict__ brow = bary + (size_t)(rowok ? krow : 0) * 240;
  const int ntbase = bn * 24 + wn * 6;

  // bary regs for chunks ch+1 (q), ch+2 (r), ch+3 (s) — depth-3 prefetch
  float2 q0, q1, q2, r0, r1, r2, s0, s1, s2;
  // gather data in flight for next chunk
  float4 ga0, gb0, ga1, gb1, ga2, gb2;

  auto ldbary = [&](int c, float2& p0, float2& p1, float2& p2) {
    if (c < 40 && rowok) {
      const float* bp = brow + c * 6;
      p0 = *(const float2*)(bp);
      p1 = *(const float2*)(bp + 2);
      p2 = *(const float2*)(bp + 4);
    } else {
      p0 = make_float2(0.f, 0.f); p1 = p0; p2 = p0;   // gather row 0, weight 0
    }
  };
  // issue gather loads for chunk c using (q0,q1,q2) — results land in ga*/gb*
  auto issue = [&](int c) {
    if (c == 40) {   // center chunk: A[k][1280+f] = ms[k][f]
      const float* m = ms + (size_t)(rowok ? krow : 0) * 32 + af0;
      ga0 = *(const float4*)m; gb0 = *(const float4*)(m + 4);
      ga1 = make_float4(0.f, 0.f, 0.f, 0.f); gb1 = ga1; ga2 = ga1; gb2 = ga1;
    } else {
      const float* m0 = ms + ((size_t)(int)q0.x) * 32 + af0;
      const float* m1 = ms + ((size_t)(int)q1.x) * 32 + af0;
      const float* m2 = ms + ((size_t)(int)q2.x) * 32 + af0;
      ga0 = *(const float4*)m0; gb0 = *(const float4*)(m0 + 4);
      ga1 = *(const float4*)m1; gb1 = *(const float4*)(m1 + 4);
      ga2 = *(const float4*)m2; gb2 = *(const float4*)(m2 + 4);
    }
  };
  // wait (implicit via reg deps), interpolate, convert, LDS-write
  auto commit = [&](int c, int buf) {
    float w0, w1, w2;
    if (c == 40) { w0 = rowok ? 1.f : 0.f; w1 = 0.f; w2 = 0.f; }
    else         { w0 = q0.y; w1 = q1.y; w2 = q2.y; }
    float v[8];
    v[0] = w0 * ga0.x + w1 * ga1.x + w2 * ga2.x;
    v[1] = w0 * ga0.y + w1 * ga1.y + w2 * ga2.y;
    v[2] = w0 * ga0.z + w1 * ga1.z + w2 * ga2.z;
    v[3] = w0 * ga0.w + w1 * ga1.w + w2 * ga2.w;
    v[4] = w0 * gb0.x + w1 * gb1.x + w2 * gb2.x;
    v[5] = w0 * gb0.y + w1 * gb1.y + w2 * gb2.y;
    v[6] = w0 * gb0.z + w1 * gb1.z + w2 * gb2.z;
    v[7] = w0 * gb0.w + w1 * gb1.w + w2 * gb2.w;
    short8 t;
#pragma unroll
    for (int j = 0; j < 8; ++j) t[j] = f2bf(v[j]);
    *reinterpret_cast<short8*>(&Atile[buf][arow][af0]) = t;
  };

  floatx4 acc[4][6];
#pragma unroll
  for (int mi = 0; mi < 4; ++mi)
#pragma unroll
    for (int nj = 0; nj < 6; ++nj) acc[mi][nj] = (floatx4)0.f;

  // ---- prologue: chunk 0 built (one exposed-latency stall, once) ----
  ldbary(0, q0, q1, q2);
  issue(0);
  ldbary(1, r0, r1, r2);   // hmm: these become q at ch=0
  ldbary(2, s0, s1, s2);
  commit(0, 0);
  // preload B-fragments for chunk 0
  short8 bf[6], nbf[6];
  {
    const short* bp0 = Bp + ((size_t)(0 * 48 + ntbase) * 64 + lane) * 8;
#pragma unroll
    for (int j = 0; j < 6; ++j)
      bf[j] = *reinterpret_cast<const short8*>(bp0 + (size_t)j * 512);
  }
  // rotate so that at loop entry (q,r,s) = bary[ch+1], bary[ch+2], bary[ch+3]
  q0 = r0; q1 = r1; q2 = r2;
  r0 = s0; r1 = s1; r2 = s2;
  ldbary(3, s0, s1, s2);
  __syncthreads();

  for (int ch = 0; ch <= 40; ++ch) {
    const int cur = ch & 1;
    if (ch < 40) {
      issue(ch + 1);             // gathers -> regs, addresses from q (landed)
    }
    // afrag ds_reads (independent of in-flight gathers)
    short8 af[4];
    const short* ap = &Atile[cur][wm * 64 + l15][kh * 8];
#pragma unroll
    for (int mi = 0; mi < 4; ++mi)
      af[mi] = *reinterpret_cast<const short8*>(ap + mi * 16 * 40);
    // prefetch next chunk's B-fragments
    const int chn = (ch < 40) ? ch + 1 : 40;
    const short* bnp = Bp + ((size_t)(chn * 48 + ntbase) * 64 + lane) * 8;
#pragma unroll
    for (int j = 0; j < 6; ++j)
      nbf[j] = *reinterpret_cast<const short8*>(bnp + (size_t)j * 512);
    // MFMAs on current buffer (cover gather latency)
#pragma unroll
    for (int nj = 0; nj < 6; ++nj)
#pragma unroll
      for (int mi = 0; mi < 4; ++mi)
        acc[mi][nj] = __builtin_amdgcn_mfma_f32_16x16x32_bf16(af[mi], bf[nj], acc[mi][nj], 0, 0, 0);
    if (ch < 40) {
      commit(ch + 1, cur ^ 1);   // wait gathers, convert, ds_write next buf
      // rotate bary pipeline: load 3 ahead
      q0 = r0; q1 = r1; q2 = r2;
      r0 = s0; r1 = s1; r2 = s2;
      ldbary(ch + 4, s0, s1, s2);
    }
    __syncthreads();
#pragma unroll
    for (int j = 0; j < 6; ++j) bf[j] = nbf[j];
  }

  // epilogue: bias + relu, write out[k,o,t] = out[k*864 + n]; duplicate o=8 from o=0
  const int row0 = kbase + wm * 64 + kh * 4;
  const int col0 = bn * 384 + wn * 96;
#pragma unroll
  for (int mi = 0; mi < 4; ++mi) {
    const int rb = row0 + mi * 16;
#pragma unroll
    for (int nj = 0; nj < 6; ++nj) {
      const int n = col0 + nj * 16 + l15;
      const float bsv = bias[n % 96];
      const bool dup = (n < 96);
#pragma unroll
      for (int i = 0; i < 4; ++i) {
        const int r = rb + i;
        if (r < KPTS) {
          float vv = fmaxf(acc[mi][nj][i] + bsv, 0.f);
          out[(size_t)r * OUT_STRIDE + n] = vv;
          if (dup) out[(size_t)r * OUT_STRIDE + 768 + n] = vv;
        }
      }
    }
  }
}

extern "C" void kernel_launch(void* const* d_in, const int* in_sizes, int n_in,
                              void* d_out, int out_size, void* d_ws, size_t ws_size,
                              hipStream_t stream) {
  const float* ms   = (const float*)d_in[0];  // (K,32)
  const float* bary = (const float*)d_in[1];  // (K,5,8,3,2)
  const float* kern = (const float*)d_in[2];  // (5,8,5,8)
  const float* tw   = (const float*)d_in[3];  // (96,5,8,32)
  const float* sw   = (const float*)d_in[4];  // (96,1,32)
  const float* bias = (const float*)d_in[5];  // (96,)
  float* out = (float*)d_out;
  short* Bp = (short*)d_ws;                   // 41*48*64*8 bf16 ≈ 2.02 MB

  hipLaunchKernelGGL(prep_B, dim3(48, 41), dim3(64), 0, stream, kern, tw, sw, Bp);
  hipLaunchKernelGGL(conv_main, dim3(782, 2), dim3(THREADS), 0, stream,
                     ms, bary, bias, Bp, out);
}

// Round 3
// 469.799 us; speedup vs baseline: 1.4979x; 1.1388x over previous
//
#include <hip/hip_runtime.h>
#include <hip/hip_bf16.h>
#include <stdint.h>

// ConvIntrinsic: fused  out[k,o,t] = relu( Σ_f sw[t,f]·ms[k,f]
//                + Σ_{x,y,f} W3[o,t,x,y,f]·interp0[k,x,y,f] + bias[t] )
// => GEMM (K=100000 × 1312) @ (1312 × 768), o=8 column duplicates o=0.
//
// R2: BM=64 × BN=768 single block per k-tile (halves bary+gather EA traffic
// vs the R1 bn-split), 2-chunk-ahead gather pipelining (E/O register sets:
// gathers are a full iteration in flight before commit), 1-ahead bary
// register sets (nontemporal loads), nontemporal output stores to protect
// L2 for the random ms gathers.

typedef __attribute__((ext_vector_type(8))) short short8;
typedef __attribute__((ext_vector_type(4))) short short4v;
typedef __attribute__((ext_vector_type(4))) float floatx4;
typedef __attribute__((ext_vector_type(2))) float fx2;

#define KPTS 100000
#define OUT_STRIDE 864   // 9*96
#define BM 64
#define THREADS 512

__device__ __forceinline__ short f2bf(float x) {
  union { float f; uint32_t u; } c; c.f = x;
  uint32_t u = c.u;
  u += 0x7FFFu + ((u >> 16) & 1u);   // round-to-nearest-even
  return (short)(u >> 16);
}

// ---------------- prep: pack B in MFMA fragment layout --------------------
// Bp[ch][ntile][lane][j] = B[c = ch*32 + (lane>>4)*8 + j][n = ntile*16 + (lane&15)]
__global__ void prep_B(const float* __restrict__ kern,
                       const float* __restrict__ tw,
                       const float* __restrict__ sw,
                       short* __restrict__ Bp) {
  const int ntile = blockIdx.x;   // 0..47
  const int ch    = blockIdx.y;   // 0..40
  const int lane  = threadIdx.x;  // 0..63
  const int n = ntile * 16 + (lane & 15);
  const int o = n / 96;
  const int t = n - o * 96;
  const int fb = (lane >> 4) * 8;

  short8 v;
  if (ch < 40) {
    float kcol[40];
#pragma unroll
    for (int ra = 0; ra < 40; ++ra) kcol[ra] = kern[ra * 40 + ch];
#pragma unroll
    for (int j = 0; j < 8; ++j) {
      const int f = fb + j;
      float acc = 0.f;
      for (int r = 0; r < 5; ++r) {
#pragma unroll
        for (int a = 0; a < 8; ++a) {
          acc += kcol[r * 8 + a] * tw[((t * 5 + r) * 8 + ((a + o) & 7)) * 32 + f];
        }
      }
      v[j] = f2bf(acc);
    }
  } else {
#pragma unroll
    for (int j = 0; j < 8; ++j) v[j] = f2bf(sw[t * 32 + fb + j]);
  }
  *reinterpret_cast<short8*>(Bp + ((size_t)(ch * 48 + ntile) * 64 + lane) * 8) = v;
}

// ---------------- main fused GEMM ----------------------------------------
__global__ __launch_bounds__(THREADS, 1) void conv_main(
    const float* __restrict__ ms,
    const float* __restrict__ bary,
    const float* __restrict__ bias,
    const short* __restrict__ Bp,
    float* __restrict__ out) {
  __shared__ short Atile[2][BM][40];   // stride 40 shorts: conflict-free

  const int kbase = blockIdx.x * BM;
  const int tid = threadIdx.x;
  const int lane = tid & 63;
  const int wn = tid >> 6;             // 0..7  (wave n-group: cols wn*96)
  const int l15 = lane & 15;
  const int kh = lane >> 4;            // 0..3

  // A-build role: 8 threads per row, 4 f-columns each
  const int arow = tid >> 3;           // 0..63
  const int af0 = (tid & 7) * 4;       // 0,4,...,28
  const int krow = kbase + arow;
  const bool rowok = krow < KPTS;
  const float* __restrict__ brow = bary + (size_t)(rowok ? krow : 0) * 240;

  // bary register sets (chunk parity): loaded 1 iter before use
  fx2 bE0, bE1, bE2, bO0, bO1, bO2;
  // gather register sets (chunk parity): issued 1 full iter before commit
  floatx4 eG0, eG1, eG2, oG0, oG1, oG2;
  float eW0, eW1, eW2, oW0, oW1, oW2;

  auto ldbary = [&](int c, fx2& p0, fx2& p1, fx2& p2) {
    if (rowok) {
      const fx2* bp = (const fx2*)(brow + c * 6);
      p0 = __builtin_nontemporal_load(bp);
      p1 = __builtin_nontemporal_load(bp + 1);
      p2 = __builtin_nontemporal_load(bp + 2);
    } else {
      p0 = (fx2)0.f; p1 = (fx2)0.f; p2 = (fx2)0.f;
    }
  };
  auto issueG = [&](int c, const fx2& p0, const fx2& p1, const fx2& p2,
                    floatx4& A, floatx4& B, floatx4& C,
                    float& W0, float& W1, float& W2) {
    if (c == 40) {   // center chunk: A[k][1280+f] = ms[k][f]
      A = *(const floatx4*)(ms + (size_t)(rowok ? krow : 0) * 32 + af0);
      B = (floatx4)0.f; C = (floatx4)0.f;
      W0 = rowok ? 1.f : 0.f; W1 = 0.f; W2 = 0.f;
    } else {
      A = *(const floatx4*)(ms + ((size_t)(int)p0.x) * 32 + af0);
      B = *(const floatx4*)(ms + ((size_t)(int)p1.x) * 32 + af0);
      C = *(const floatx4*)(ms + ((size_t)(int)p2.x) * 32 + af0);
      W0 = p0.y; W1 = p1.y; W2 = p2.y;
    }
  };
  auto commitG = [&](const floatx4& A, const floatx4& B, const floatx4& C,
                     float W0, float W1, float W2, int buf) {
    short4v s;
    s[0] = f2bf(W0 * A[0] + W1 * B[0] + W2 * C[0]);
    s[1] = f2bf(W0 * A[1] + W1 * B[1] + W2 * C[1]);
    s[2] = f2bf(W0 * A[2] + W1 * B[2] + W2 * C[2]);
    s[3] = f2bf(W0 * A[3] + W1 * B[3] + W2 * C[3]);
    *reinterpret_cast<short4v*>(&Atile[buf][arow][af0]) = s;
  };

  short8 bf[6], nbf[6];
  auto loadB = [&](int c, short8* dst) {
    const short* bp = Bp + ((size_t)(c * 48 + wn * 6) * 64 + lane) * 8;
#pragma unroll
    for (int j = 0; j < 6; ++j)
      dst[j] = *reinterpret_cast<const short8*>(bp + (size_t)j * 512);
  };

  floatx4 acc[4][6];
#pragma unroll
  for (int mi = 0; mi < 4; ++mi)
#pragma unroll
    for (int nj = 0; nj < 6; ++nj) acc[mi][nj] = (floatx4)0.f;

  // ---- prologue ----
  {
    fx2 t0, t1, t2;
    ldbary(0, t0, t1, t2);
    issueG(0, t0, t1, t2, eG0, eG1, eG2, eW0, eW1, eW2);
    ldbary(1, t0, t1, t2);
    issueG(1, t0, t1, t2, oG0, oG1, oG2, oW0, oW1, oW2);
  }
  ldbary(2, bE0, bE1, bE2);           // for issue(2) at iter 0
  commitG(eG0, eG1, eG2, eW0, eW1, eW2, 0);   // chunk 0 -> Atile[0]
  loadB(0, bf);
  __syncthreads();

  // iter ch: issue(ch+2) with bary set (ch&1); ldbary(ch+3) -> other set;
  // MFMA chunk ch from Atile[ch&1]; commit(ch+1) -> Atile[(ch&1)^1].
#define ITER(ch, UB0, UB1, UB2, FB0, FB1, FB2,                                  \
             FG0, FG1, FG2, FW0, FW1, FW2,                                      \
             CG0, CG1, CG2, CW0, CW1, CW2, CUR)                                 \
  {                                                                             \
    if ((ch) + 2 <= 40)                                                         \
      issueG((ch) + 2, UB0, UB1, UB2, FG0, FG1, FG2, FW0, FW1, FW2);            \
    if ((ch) + 3 <= 39) ldbary((ch) + 3, FB0, FB1, FB2);                        \
    short8 af[4];                                                               \
    _Pragma("unroll")                                                           \
    for (int mi = 0; mi < 4; ++mi)                                              \
      af[mi] = *reinterpret_cast<const short8*>(&Atile[CUR][mi * 16 + l15][kh * 8]); \
    if ((ch) + 1 <= 40) loadB((ch) + 1, nbf);                                   \
    _Pragma("unroll")                                                           \
    for (int nj = 0; nj < 6; ++nj)                                              \
      _Pragma("unroll")                                                         \
      for (int mi = 0; mi < 4; ++mi)                                            \
        acc[mi][nj] = __builtin_amdgcn_mfma_f32_16x16x32_bf16(af[mi], bf[nj],   \
                                                              acc[mi][nj], 0, 0, 0); \
    if ((ch) + 1 <= 40)                                                         \
      commitG(CG0, CG1, CG2, CW0, CW1, CW2, (CUR) ^ 1);                         \
    __syncthreads();                                                            \
    _Pragma("unroll")                                                           \
    for (int j = 0; j < 6; ++j) bf[j] = nbf[j];                                 \
  }

  for (int ch = 0; ch < 40; ch += 2) {
    // even iter: use bE, fill bO; fill E gathers, commit O gathers; read Atile[0]
    ITER(ch,     bE0, bE1, bE2, bO0, bO1, bO2,
         eG0, eG1, eG2, eW0, eW1, eW2,
         oG0, oG1, oG2, oW0, oW1, oW2, 0)
    // odd iter: use bO, fill bE; fill O gathers, commit E gathers; read Atile[1]
    ITER(ch + 1, bO0, bO1, bO2, bE0, bE1, bE2,
         oG0, oG1, oG2, oW0, oW1, oW2,
         eG0, eG1, eG2, eW0, eW1, eW2, 1)
  }
  ITER(40, bE0, bE1, bE2, bO0, bO1, bO2,
       eG0, eG1, eG2, eW0, eW1, eW2,
       oG0, oG1, oG2, oW0, oW1, oW2, 0)
#undef ITER

  // epilogue: bias + relu; out[k,o,t] = out[k*864 + n]; o=8 duplicates o=0
#pragma unroll
  for (int mi = 0; mi < 4; ++mi) {
    const int rb = kbase + mi * 16 + kh * 4;
#pragma unroll
    for (int nj = 0; nj < 6; ++nj) {
      const int n = wn * 96 + nj * 16 + l15;
      const float bsv = bias[nj * 16 + l15];
      const bool dup = (wn == 0);
#pragma unroll
      for (int i = 0; i < 4; ++i) {
        const int r = rb + i;
        if (r < KPTS) {
          float vv = fmaxf(acc[mi][nj][i] + bsv, 0.f);
          __builtin_nontemporal_store(vv, &out[(size_t)r * OUT_STRIDE + n]);
          if (dup)
            __builtin_nontemporal_store(vv, &out[(size_t)r * OUT_STRIDE + 768 + n]);
        }
      }
    }
  }
}

extern "C" void kernel_launch(void* const* d_in, const int* in_sizes, int n_in,
                              void* d_out, int out_size, void* d_ws, size_t ws_size,
                              hipStream_t stream) {
  const float* ms   = (const float*)d_in[0];  // (K,32)
  const float* bary = (const float*)d_in[1];  // (K,5,8,3,2)
  const float* kern = (const float*)d_in[2];  // (5,8,5,8)
  const float* tw   = (const float*)d_in[3];  // (96,5,8,32)
  const float* sw   = (const float*)d_in[4];  // (96,1,32)
  const float* bias = (const float*)d_in[5];  // (96,)
  float* out = (float*)d_out;
  short* Bp = (short*)d_ws;                   // 41*48*64*8 bf16 ≈ 2.02 MB

  hipLaunchKernelGGL(prep_B, dim3(48, 41), dim3(64), 0, stream, kern, tw, sw, Bp);
  hipLaunchKernelGGL(conv_main, dim3(1563), dim3(THREADS), 0, stream,
                     ms, bary, bias, Bp, out);
}

// Round 4
// 461.608 us; speedup vs baseline: 1.5245x; 1.0177x over previous
//
#include <hip/hip_runtime.h>
#include <hip/hip_bf16.h>
#include <stdint.h>

// ConvIntrinsic: fused  out[k,o,t] = relu( Σ_f sw[t,f]·ms[k,f]
//                + Σ_{x,y,f} W3[o,t,x,y,f]·interp0[k,x,y,f] + bias[t] )
// => GEMM (K=100000 × 1312) @ (1312 × 768), o=8 column duplicates o=0.
//
// R3: replace __syncthreads() (which drains vmcnt(0) -> flattens the gather
// pipeline to depth 0, ~4000 cy exposed stall/chunk) with raw
// "s_waitcnt lgkmcnt(0); s_barrier" so global loads (gathers, bary, B-frags)
// stay in flight across barriers with compiler-counted vmcnt at use (T4).
// Also: parity-alternating B-frag register sets (no per-iter reg copies),
// plain output stores (nontemporal inflated WRITE 339->436 MB in R2).

typedef __attribute__((ext_vector_type(8))) short short8;
typedef __attribute__((ext_vector_type(4))) short short4v;
typedef __attribute__((ext_vector_type(4))) float floatx4;
typedef __attribute__((ext_vector_type(2))) float fx2;

#define KPTS 100000
#define OUT_STRIDE 864   // 9*96
#define BM 64
#define THREADS 512

// raw workgroup barrier: LDS ordering enforced (lgkmcnt(0)), global loads
// deliberately left in flight (no vmcnt drain).
#define BARRIER() asm volatile("s_waitcnt lgkmcnt(0)\n\ts_barrier" ::: "memory")

__device__ __forceinline__ short f2bf(float x) {
  union { float f; uint32_t u; } c; c.f = x;
  uint32_t u = c.u;
  u += 0x7FFFu + ((u >> 16) & 1u);   // round-to-nearest-even
  return (short)(u >> 16);
}

// ---------------- prep: pack B in MFMA fragment layout --------------------
// Bp[ch][ntile][lane][j] = B[c = ch*32 + (lane>>4)*8 + j][n = ntile*16 + (lane&15)]
__global__ void prep_B(const float* __restrict__ kern,
                       const float* __restrict__ tw,
                       const float* __restrict__ sw,
                       short* __restrict__ Bp) {
  const int ntile = blockIdx.x;   // 0..47
  const int ch    = blockIdx.y;   // 0..40
  const int lane  = threadIdx.x;  // 0..63
  const int n = ntile * 16 + (lane & 15);
  const int o = n / 96;
  const int t = n - o * 96;
  const int fb = (lane >> 4) * 8;

  short8 v;
  if (ch < 40) {
    float kcol[40];
#pragma unroll
    for (int ra = 0; ra < 40; ++ra) kcol[ra] = kern[ra * 40 + ch];
#pragma unroll
    for (int j = 0; j < 8; ++j) {
      const int f = fb + j;
      float acc = 0.f;
      for (int r = 0; r < 5; ++r) {
#pragma unroll
        for (int a = 0; a < 8; ++a) {
          acc += kcol[r * 8 + a] * tw[((t * 5 + r) * 8 + ((a + o) & 7)) * 32 + f];
        }
      }
      v[j] = f2bf(acc);
    }
  } else {
#pragma unroll
    for (int j = 0; j < 8; ++j) v[j] = f2bf(sw[t * 32 + fb + j]);
  }
  *reinterpret_cast<short8*>(Bp + ((size_t)(ch * 48 + ntile) * 64 + lane) * 8) = v;
}

// ---------------- main fused GEMM ----------------------------------------
__global__ __launch_bounds__(THREADS, 1) void conv_main(
    const float* __restrict__ ms,
    const float* __restrict__ bary,
    const float* __restrict__ bias,
    const short* __restrict__ Bp,
    float* __restrict__ out) {
  __shared__ short Atile[2][BM][40];   // stride 40 shorts: conflict-free

  const int kbase = blockIdx.x * BM;
  const int tid = threadIdx.x;
  const int lane = tid & 63;
  const int wn = tid >> 6;             // 0..7  (wave n-group: cols wn*96)
  const int l15 = lane & 15;
  const int kh = lane >> 4;            // 0..3

  // A-build role: 8 threads per row, 4 f-columns each
  const int arow = tid >> 3;           // 0..63
  const int af0 = (tid & 7) * 4;       // 0,4,...,28
  const int krow = kbase + arow;
  const bool rowok = krow < KPTS;
  const float* __restrict__ brow = bary + (size_t)(rowok ? krow : 0) * 240;

  // bary register sets (chunk parity): loaded 1 iter before use
  fx2 bE0, bE1, bE2, bO0, bO1, bO2;
  // gather register sets (chunk parity): issued 1 full iter before commit
  floatx4 eG0, eG1, eG2, oG0, oG1, oG2;
  float eW0, eW1, eW2, oW0, oW1, oW2;

  auto ldbary = [&](int c, fx2& p0, fx2& p1, fx2& p2) {
    if (rowok) {
      const fx2* bp = (const fx2*)(brow + c * 6);
      p0 = __builtin_nontemporal_load(bp);
      p1 = __builtin_nontemporal_load(bp + 1);
      p2 = __builtin_nontemporal_load(bp + 2);
    } else {
      p0 = (fx2)0.f; p1 = (fx2)0.f; p2 = (fx2)0.f;
    }
  };
  auto issueG = [&](int c, const fx2& p0, const fx2& p1, const fx2& p2,
                    floatx4& A, floatx4& B, floatx4& C,
                    float& W0, float& W1, float& W2) {
    if (c == 40) {   // center chunk: A[k][1280+f] = ms[k][f]
      A = *(const floatx4*)(ms + (size_t)(rowok ? krow : 0) * 32 + af0);
      B = (floatx4)0.f; C = (floatx4)0.f;
      W0 = rowok ? 1.f : 0.f; W1 = 0.f; W2 = 0.f;
    } else {
      A = *(const floatx4*)(ms + ((size_t)(int)p0.x) * 32 + af0);
      B = *(const floatx4*)(ms + ((size_t)(int)p1.x) * 32 + af0);
      C = *(const floatx4*)(ms + ((size_t)(int)p2.x) * 32 + af0);
      W0 = p0.y; W1 = p1.y; W2 = p2.y;
    }
  };
  auto commitG = [&](const floatx4& A, const floatx4& B, const floatx4& C,
                     float W0, float W1, float W2, int buf) {
    short4v s;
    s[0] = f2bf(W0 * A[0] + W1 * B[0] + W2 * C[0]);
    s[1] = f2bf(W0 * A[1] + W1 * B[1] + W2 * C[1]);
    s[2] = f2bf(W0 * A[2] + W1 * B[2] + W2 * C[2]);
    s[3] = f2bf(W0 * A[3] + W1 * B[3] + W2 * C[3]);
    *reinterpret_cast<short4v*>(&Atile[buf][arow][af0]) = s;
  };

  short8 bfA[6], bfB[6];
  auto loadB = [&](int c, short8* dst) {
    const short* bp = Bp + ((size_t)(c * 48 + wn * 6) * 64 + lane) * 8;
#pragma unroll
    for (int j = 0; j < 6; ++j)
      dst[j] = *reinterpret_cast<const short8*>(bp + (size_t)j * 512);
  };

  floatx4 acc[4][6];
#pragma unroll
  for (int mi = 0; mi < 4; ++mi)
#pragma unroll
    for (int nj = 0; nj < 6; ++nj) acc[mi][nj] = (floatx4)0.f;

  // ---- prologue ----
  {
    fx2 t0, t1, t2;
    ldbary(0, t0, t1, t2);
    issueG(0, t0, t1, t2, eG0, eG1, eG2, eW0, eW1, eW2);
    ldbary(1, t0, t1, t2);
    issueG(1, t0, t1, t2, oG0, oG1, oG2, oW0, oW1, oW2);
  }
  ldbary(2, bE0, bE1, bE2);           // for issue(2) at iter 0
  commitG(eG0, eG1, eG2, eW0, eW1, eW2, 0);   // chunk 0 -> Atile[0]
  loadB(0, bfA);
  BARRIER();

  // iter ch: issue(ch+2) with bary set (ch&1); ldbary(ch+3) -> other set;
  // MFMA chunk ch from Atile[ch&1] with B-set BF; loadB(ch+1) -> NBF;
  // commit(ch+1) -> Atile[(ch&1)^1]; raw barrier (global loads stay in flight).
#define ITER(ch, UB0, UB1, UB2, FB0, FB1, FB2,                                  \
             FG0, FG1, FG2, FW0, FW1, FW2,                                      \
             CG0, CG1, CG2, CW0, CW1, CW2, CUR, BF, NBF)                        \
  {                                                                             \
    if ((ch) + 2 <= 40)                                                         \
      issueG((ch) + 2, UB0, UB1, UB2, FG0, FG1, FG2, FW0, FW1, FW2);            \
    if ((ch) + 3 <= 39) ldbary((ch) + 3, FB0, FB1, FB2);                        \
    short8 af[4];                                                               \
    _Pragma("unroll")                                                           \
    for (int mi = 0; mi < 4; ++mi)                                              \
      af[mi] = *reinterpret_cast<const short8*>(&Atile[CUR][mi * 16 + l15][kh * 8]); \
    if ((ch) + 1 <= 40) loadB((ch) + 1, NBF);                                   \
    _Pragma("unroll")                                                           \
    for (int nj = 0; nj < 6; ++nj)                                              \
      _Pragma("unroll")                                                         \
      for (int mi = 0; mi < 4; ++mi)                                            \
        acc[mi][nj] = __builtin_amdgcn_mfma_f32_16x16x32_bf16(af[mi], BF[nj],   \
                                                              acc[mi][nj], 0, 0, 0); \
    if ((ch) + 1 <= 40)                                                         \
      commitG(CG0, CG1, CG2, CW0, CW1, CW2, (CUR) ^ 1);                         \
    BARRIER();                                                                  \
  }

  for (int ch = 0; ch < 40; ch += 2) {
    // even iter: use bE, fill bO; fill E gathers, commit O gathers; Atile[0]; B=bfA
    ITER(ch,     bE0, bE1, bE2, bO0, bO1, bO2,
         eG0, eG1, eG2, eW0, eW1, eW2,
         oG0, oG1, oG2, oW0, oW1, oW2, 0, bfA, bfB)
    // odd iter: use bO, fill bE; fill O gathers, commit E gathers; Atile[1]; B=bfB
    ITER(ch + 1, bO0, bO1, bO2, bE0, bE1, bE2,
         oG0, oG1, oG2, oW0, oW1, oW2,
         eG0, eG1, eG2, eW0, eW1, eW2, 1, bfB, bfA)
  }
  ITER(40, bE0, bE1, bE2, bO0, bO1, bO2,
       eG0, eG1, eG2, eW0, eW1, eW2,
       oG0, oG1, oG2, oW0, oW1, oW2, 0, bfA, bfB)
#undef ITER

  // epilogue: bias + relu; out[k,o,t] = out[k*864 + n]; o=8 duplicates o=0
#pragma unroll
  for (int mi = 0; mi < 4; ++mi) {
    const int rb = kbase + mi * 16 + kh * 4;
#pragma unroll
    for (int nj = 0; nj < 6; ++nj) {
      const int n = wn * 96 + nj * 16 + l15;
      const float bsv = bias[nj * 16 + l15];
      const bool dup = (wn == 0);
#pragma unroll
      for (int i = 0; i < 4; ++i) {
        const int r = rb + i;
        if (r < KPTS) {
          float vv = fmaxf(acc[mi][nj][i] + bsv, 0.f);
          out[(size_t)r * OUT_STRIDE + n] = vv;
          if (dup) out[(size_t)r * OUT_STRIDE + 768 + n] = vv;
        }
      }
    }
  }
}

extern "C" void kernel_launch(void* const* d_in, const int* in_sizes, int n_in,
                              void* d_out, int out_size, void* d_ws, size_t ws_size,
                              hipStream_t stream) {
  const float* ms   = (const float*)d_in[0];  // (K,32)
  const float* bary = (const float*)d_in[1];  // (K,5,8,3,2)
  const float* kern = (const float*)d_in[2];  // (5,8,5,8)
  const float* tw   = (const float*)d_in[3];  // (96,5,8,32)
  const float* sw   = (const float*)d_in[4];  // (96,1,32)
  const float* bias = (const float*)d_in[5];  // (96,)
  float* out = (float*)d_out;
  short* Bp = (short*)d_ws;                   // 41*48*64*8 bf16 ≈ 2.02 MB

  hipLaunchKernelGGL(prep_B, dim3(48, 41), dim3(64), 0, stream, kern, tw, sw, Bp);
  hipLaunchKernelGGL(conv_main, dim3(1563), dim3(THREADS), 0, stream,
                     ms, bary, bias, Bp, out);
}